// Round 12
// baseline (625.369 us; speedup 1.0000x reference)
//
#include <hip/hip_runtime.h>
#include <hip/hip_fp16.h>

constexpr int Bn = 2, C = 21, H = 256, W = 256, HW = H * W;
constexpr int CQ = 6;                       // channel quads (C padded to 24)
constexpr int TW = 32, TH = 16, NT = 1024;  // output tile / block size
constexpr int HALO = 10;                    // 5 iterations x 2-halo
constexpr int EH = TH + 2 * HALO;           // 36
constexpr int EW = TW + 2 * HALO;           // 52
constexpr int NEC = EH * EW;                // 1872

// Normalized spatial gaussian (sigma=5): exp(-(dy^2+dx^2)/50)/S, S=23.1036923.
__device__ constexpr float SKN[25] = {
    0.03688346f, 0.03916421f, 0.03995538f, 0.03916421f, 0.03688346f,
    0.03916421f, 0.04158598f, 0.04242608f, 0.04158598f, 0.03916421f,
    0.03995538f, 0.04242608f, 0.04328314f, 0.04242608f, 0.03995538f,
    0.03916421f, 0.04158598f, 0.04242608f, 0.04158598f, 0.03916421f,
    0.03688346f, 0.03916421f, 0.03995538f, 0.03916421f, 0.03688346f};

union H2U { __half2 h; unsigned int u; };

// ---------------------------------------------------------------------------
// One tap-row for a horizontal PAIR of cells (ex0, ex0+1). Reads 6 img
// positions + per quad 3 x ds_read_b128 (6 q-cells), accumulates 5 taps into
// each cell's fp16 partials. DR is compile-time (SKN indices fold to
// literals; row choice of A/B partial is made at the call site).
// ---------------------------------------------------------------------------
template <int DR>
__device__ __forceinline__ void row_taps(
        int ey, int ex0, const float4* __restrict__ simg,
        const __half2 (*bufQ)[EH][EW][2],
        const float4& ctr0, const float4& ctr1,
        __half2 (&a0)[CQ][2], __half2 (&a1)[CQ][2]) {
    const int ly = ey - 2 + DR;
    float4 nb[6];
#pragma unroll
    for (int j = 0; j < 6; ++j) nb[j] = simg[ly * EW + (ex0 - 2) + j];
    unsigned int w0[5], w1[5];
#pragma unroll
    for (int c = 0; c < 5; ++c) {
        const float sk = SKN[DR * 5 + c];
        float d0 = nb[c].x - ctr0.x, d1 = nb[c].y - ctr0.y, d2 = nb[c].z - ctr0.z;
        float wv = sk * __expf(-50.f * (d0 * d0 + d1 * d1 + d2 * d2));
        if (DR == 2 && c == 2) wv += 1.0f;   // identity (delta) spatial conv
        H2U cv; cv.h = __float2half2_rn(wv); w0[c] = cv.u;
        float e0 = nb[c + 1].x - ctr1.x, e1 = nb[c + 1].y - ctr1.y,
              e2 = nb[c + 1].z - ctr1.z;
        float wu = sk * __expf(-50.f * (e0 * e0 + e1 * e1 + e2 * e2));
        if (DR == 2 && c == 2) wu += 1.0f;
        cv.h = __float2half2_rn(wu); w1[c] = cv.u;
    }
#pragma unroll
    for (int g = 0; g < CQ; ++g) {
        const uint4 r0 = *reinterpret_cast<const uint4*>(&bufQ[g][ly][ex0 - 2][0]);
        const uint4 r1 = *reinterpret_cast<const uint4*>(&bufQ[g][ly][ex0][0]);
        const uint4 r2 = *reinterpret_cast<const uint4*>(&bufQ[g][ly][ex0 + 2][0]);
        const unsigned int q01[6] = {r0.x, r0.z, r1.x, r1.z, r2.x, r2.z};
        const unsigned int q23[6] = {r0.y, r0.w, r1.y, r1.w, r2.y, r2.w};
#pragma unroll
        for (int c = 0; c < 5; ++c) {
            H2U wv; wv.u = w0[c];
            H2U p0; p0.u = q01[c]; H2U p1; p1.u = q23[c];
            a0[g][0] = __hfma2(wv.h, p0.h, a0[g][0]);
            a0[g][1] = __hfma2(wv.h, p1.h, a0[g][1]);
            H2U wu; wu.u = w1[c];
            H2U s0; s0.u = q01[c + 1]; H2U s1; s1.u = q23[c + 1];
            a1[g][0] = __hfma2(wu.h, s0.h, a1[g][0]);
            a1[g][1] = __hfma2(wu.h, s1.h, a1[g][1]);
        }
    }
}

// ---------------------------------------------------------------------------
// Compat + softmax finish for one cell -> vals[24] (q values, 0-padded).
// ---------------------------------------------------------------------------
__device__ __forceinline__ void cell_finish(
        bool valid, int fast, const float* __restrict__ lgp,
        const float* __restrict__ scm, const float (&m)[24],
        float (&vals)[24]) {
    if (!valid) {
#pragma unroll
        for (int c = 0; c < 24; ++c) vals[c] = 0.f;
        return;
    }
    float z[C], mx = -1e30f;
    if (fast) {                       // compat == -I: z = logits + m
#pragma unroll
        for (int c = 0; c < C; ++c) {
            z[c] = lgp[(size_t)c * HW] + m[c]; mx = fmaxf(mx, z[c]);
        }
    } else {                          // general matvec, thread-local
#pragma unroll
        for (int c = 0; c < C; ++c) {
            float pw = 0.f;
#pragma unroll
            for (int j = 0; j < C; ++j) pw += scm[c * C + j] * m[j];
            z[c] = lgp[(size_t)c * HW] - pw; mx = fmaxf(mx, z[c]);
        }
    }
    float ssum = 0.f;
#pragma unroll
    for (int c = 0; c < C; ++c) { z[c] = __expf(z[c] - mx); ssum += z[c]; }
    const float inv = 1.f / ssum;
#pragma unroll
    for (int c = 0; c < 24; ++c) vals[c] = (c < C) ? z[c] * inv : 0.f;
}

// ---------------------------------------------------------------------------
// One mean-field iteration over the shrinking region, pair-per-thread.
// ---------------------------------------------------------------------------
template <int MARGIN, bool FINAL>
__device__ __forceinline__ void mf_iter(
        int tid, int b, int y0, int x0, int fast,
        const float* __restrict__ lgb, const float* __restrict__ scm,
        __half2 (*bufQ)[EH][EW][2], const float4* __restrict__ simg,
        float* __restrict__ outp) {
    constexpr int HT_ = EH - 2 * MARGIN, WT_ = EW - 2 * MARGIN;
    constexpr int WP = WT_ / 2, NPAIR = HT_ * WP;   // <= 768 < NT always
    const bool act = tid < NPAIR;
    unsigned int nq0[12], nq1[12];
    int ey = 0, ex0 = 0;
    if (act) {
        const int pr = tid / WP, pc = tid % WP;
        ey = MARGIN + pr; ex0 = MARGIN + 2 * pc;
        const int gy = y0 + ey - HALO, gx0 = x0 + ex0 - HALO;
        const bool gyok = (unsigned)gy < H;
        const bool v0 = FINAL || (gyok && (unsigned)gx0 < W);
        const bool v1 = FINAL || (gyok && (unsigned)(gx0 + 1) < W);

        const float4 ctr0 = simg[ey * EW + ex0];
        const float4 ctr1 = simg[ey * EW + ex0 + 1];
        const __half2 zero2 = __float2half2_rn(0.f);
        __half2 aA0[CQ][2], aB0[CQ][2], aA1[CQ][2], aB1[CQ][2];
#pragma unroll
        for (int g = 0; g < CQ; ++g) {
            aA0[g][0] = zero2; aA0[g][1] = zero2;
            aB0[g][0] = zero2; aB0[g][1] = zero2;
            aA1[g][0] = zero2; aA1[g][1] = zero2;
            aB1[g][0] = zero2; aB1[g][1] = zero2;
        }
        row_taps<0>(ey, ex0, simg, bufQ, ctr0, ctr1, aA0, aA1);
        row_taps<1>(ey, ex0, simg, bufQ, ctr0, ctr1, aA0, aA1);
        row_taps<2>(ey, ex0, simg, bufQ, ctr0, ctr1, aA0, aA1);
        row_taps<3>(ey, ex0, simg, bufQ, ctr0, ctr1, aB0, aB1);
        row_taps<4>(ey, ex0, simg, bufQ, ctr0, ctr1, aB0, aB1);

        float m0[24], m1[24];
#pragma unroll
        for (int g = 0; g < CQ; ++g) {
            float2 lA = __half22float2(aA0[g][0]), lB = __half22float2(aB0[g][0]);
            float2 hA = __half22float2(aA0[g][1]), hB = __half22float2(aB0[g][1]);
            m0[4 * g + 0] = lA.x + lB.x; m0[4 * g + 1] = lA.y + lB.y;
            m0[4 * g + 2] = hA.x + hB.x; m0[4 * g + 3] = hA.y + hB.y;
            lA = __half22float2(aA1[g][0]); lB = __half22float2(aB1[g][0]);
            hA = __half22float2(aA1[g][1]); hB = __half22float2(aB1[g][1]);
            m1[4 * g + 0] = lA.x + lB.x; m1[4 * g + 1] = lA.y + lB.y;
            m1[4 * g + 2] = hA.x + hB.x; m1[4 * g + 3] = hA.y + hB.y;
        }

        const float* lgp0 = lgb + (v0 ? (gy * W + gx0) : 0);
        const float* lgp1 = lgb + (v1 ? (gy * W + gx0 + 1) : 0);
        float vals0[24], vals1[24];
        cell_finish(v0, fast, lgp0, scm, m0, vals0);
        cell_finish(v1, fast, lgp1, scm, m1, vals1);

        if (FINAL) {
            float* qo = outp + (size_t)b * C * HW + gy * W + gx0;
#pragma unroll
            for (int c = 0; c < C; ++c)
                *reinterpret_cast<float2*>(&qo[(size_t)c * HW]) =
                    make_float2(vals0[c], vals1[c]);
        } else {
#pragma unroll
            for (int g = 0; g < CQ; ++g) {
                H2U p0, p1;
                p0.h = __floats2half2_rn(vals0[4 * g + 0], vals0[4 * g + 1]);
                p1.h = __floats2half2_rn(vals0[4 * g + 2], vals0[4 * g + 3]);
                nq0[2 * g] = p0.u; nq0[2 * g + 1] = p1.u;
                p0.h = __floats2half2_rn(vals1[4 * g + 0], vals1[4 * g + 1]);
                p1.h = __floats2half2_rn(vals1[4 * g + 2], vals1[4 * g + 3]);
                nq1[2 * g] = p0.u; nq1[2 * g + 1] = p1.u;
            }
        }
    }
    if (!FINAL) {
        __syncthreads();                 // all reads of old q done
        if (act) {
#pragma unroll
            for (int g = 0; g < CQ; ++g)
                *reinterpret_cast<uint4*>(&bufQ[g][ey][ex0][0]) =
                    make_uint4(nq0[2 * g], nq0[2 * g + 1],
                               nq1[2 * g], nq1[2 * g + 1]);
        }
        __syncthreads();                 // new q visible
    }
}

// ---------------------------------------------------------------------------
// Mega-fused CRF: q0 = softmax(logits) staged on a 36x52 extended tile, then
// all 5 mean-field iterations in-LDS with shrinking regions. One dispatch,
// 256 blocks (1/CU) x 1024 threads. LDS = 121.6 KB.
// ---------------------------------------------------------------------------
__global__ __launch_bounds__(NT, 4) void crf_mega(
        const float* __restrict__ logits, const float* __restrict__ img,
        const float* __restrict__ compat, float* __restrict__ out) {
    __shared__ __align__(16) __half2 bufQ[CQ][EH][EW][2];  // 89856 B
    __shared__ __align__(16) float4 simg[NEC];             // 29952 B
    __shared__ float scm[C * C];                           // 1764 B

    const int b = blockIdx.z;
    const int x0 = blockIdx.x * TW, y0 = blockIdx.y * TH;
    const int tid = threadIdx.x;

    // ---- compat stage (+ -I check) ----
    int ok = 1;
    for (int i = tid; i < C * C; i += NT) {
        const float v = compat[i];
        scm[i] = v;
        ok &= (v == ((i / C == i % C) ? -1.0f : 0.0f));
    }

    const float* im  = img + (size_t)b * 3 * HW;
    const float* lgb = logits + (size_t)b * C * HW;

    // ---- stage img (f32) and q0 = softmax(logits) (fp16 quads) ----
    for (int cell = tid; cell < NEC; cell += NT) {
        const int ey = cell / EW, ex = cell % EW;
        const int gy = y0 + ey - HALO, gx = x0 + ex - HALO;
        float4 iv = make_float4(0.f, 0.f, 0.f, 0.f);
        float vals[24];
        if ((unsigned)gy < H && (unsigned)gx < W) {
            const int np = gy * W + gx;
            iv.x = im[np]; iv.y = im[HW + np]; iv.z = im[2 * HW + np];
            const float* lg = lgb + np;
            float zz[C], mx = -1e30f;
#pragma unroll
            for (int c = 0; c < C; ++c) {
                zz[c] = lg[(size_t)c * HW]; mx = fmaxf(mx, zz[c]);
            }
            float ssum = 0.f;
#pragma unroll
            for (int c = 0; c < C; ++c) { zz[c] = __expf(zz[c] - mx); ssum += zz[c]; }
            const float inv = 1.f / ssum;
#pragma unroll
            for (int c = 0; c < 24; ++c) vals[c] = (c < C) ? zz[c] * inv : 0.f;
        } else {
#pragma unroll
            for (int c = 0; c < 24; ++c) vals[c] = 0.f;
        }
        simg[cell] = iv;
#pragma unroll
        for (int g = 0; g < CQ; ++g) {
            bufQ[g][ey][ex][0] = __floats2half2_rn(vals[4 * g + 0], vals[4 * g + 1]);
            bufQ[g][ey][ex][1] = __floats2half2_rn(vals[4 * g + 2], vals[4 * g + 3]);
        }
    }
    const int fast = __syncthreads_and(ok);

    // ---- 5 fused iterations, shrinking regions (margins 2,4,6,8,10) ----
    mf_iter< 2, false>(tid, b, y0, x0, fast, lgb, scm, bufQ, simg, out);
    mf_iter< 4, false>(tid, b, y0, x0, fast, lgb, scm, bufQ, simg, out);
    mf_iter< 6, false>(tid, b, y0, x0, fast, lgb, scm, bufQ, simg, out);
    mf_iter< 8, false>(tid, b, y0, x0, fast, lgb, scm, bufQ, simg, out);
    mf_iter<10, true >(tid, b, y0, x0, fast, lgb, scm, bufQ, simg, out);
}

// ---------------------------------------------------------------------------
extern "C" void kernel_launch(void* const* d_in, const int* in_sizes, int n_in,
                              void* d_out, int out_size, void* d_ws, size_t ws_size,
                              hipStream_t stream) {
    const float* logits = (const float*)d_in[0];
    const float* img    = (const float*)d_in[1];
    // d_in[2] = gt_edges (dead code in reference)
    const float* compat = (const float*)d_in[3];
    float* out = (float*)d_out;

    dim3 g(W / TW, H / TH, Bn);      // 8 x 16 x 2 = 256 blocks = 1 per CU
    crf_mega<<<g, NT, 0, stream>>>(logits, img, compat, out);
}

// Round 13
// 87.078 us; speedup vs baseline: 7.1817x; 7.1817x over previous
//
#include <hip/hip_runtime.h>
#include <hip/hip_fp16.h>

constexpr int Bn = 2, C = 21, H = 256, W = 256, HW = H * W;
constexpr int CQ = 6;                       // channel quads (C padded to 24)
constexpr int TW = 32, TH = 16, NT = 1024;  // output tile / block size
constexpr int HALO = 10;                    // 5 iterations x 2-halo
constexpr int EH = TH + 2 * HALO;           // 36
constexpr int EW = TW + 2 * HALO;           // 52
constexpr int NEC = EH * EW;                // 1872

// Normalized spatial gaussian (sigma=5): exp(-(dy^2+dx^2)/50)/S, S=23.1036923.
__device__ constexpr float SKN[25] = {
    0.03688346f, 0.03916421f, 0.03995538f, 0.03916421f, 0.03688346f,
    0.03916421f, 0.04158598f, 0.04242608f, 0.04158598f, 0.03916421f,
    0.03995538f, 0.04242608f, 0.04328314f, 0.04242608f, 0.03995538f,
    0.03916421f, 0.04158598f, 0.04242608f, 0.04158598f, 0.03916421f,
    0.03688346f, 0.03916421f, 0.03995538f, 0.03916421f, 0.03688346f};

union H2U { __half2 h; unsigned int u; };

// ---------------------------------------------------------------------------
// One tap-row (DR = 0..4) for a cell PAIR, channel-split: this thread (half
// h of the pair, lanes 2i/2i+1) accumulates quads qoff..qoff+2 of BOTH cells.
// q reads: 3 x ds_read_b128 per quad covering 6 cells (shared by the pair).
// img: 3 b128 per half; the 2 shared middles come from the partner via shfl.
// Weights: each half computes its OWN cell's 5 weights (5 exp), then the
// pair exchanges packed weights via shfl.
// ---------------------------------------------------------------------------
template <int DR>
__device__ __forceinline__ void row_taps(
        int ey, int ex0, int half, int qoff,
        const float4* __restrict__ simg,
        const __half2 (*bufQ)[EH][EW][2],
        const float4& ctrO,
        __half2 (&a0)[3][2], __half2 (&a1)[3][2]) {
    const int ly = ey - 2 + DR;
    const float4* rowp = simg + ly * EW + (ex0 - 2);
    float4 nbr[3];
#pragma unroll
    for (int j = 0; j < 3; ++j) nbr[j] = rowp[2 * j + half];
    // own tap c in 0..4 = img at (own cell - 2 + c); own reads are c=0,2,4.
    // c=1,3 come from the partner lane.
    const float c1x = __shfl_xor(half ? nbr[0].x : nbr[1].x, 1);
    const float c1y = __shfl_xor(half ? nbr[0].y : nbr[1].y, 1);
    const float c1z = __shfl_xor(half ? nbr[0].z : nbr[1].z, 1);
    const float c3x = __shfl_xor(half ? nbr[1].x : nbr[2].x, 1);
    const float c3y = __shfl_xor(half ? nbr[1].y : nbr[2].y, 1);
    const float c3z = __shfl_xor(half ? nbr[1].z : nbr[2].z, 1);
    const float tx[5] = {nbr[0].x, c1x, nbr[1].x, c3x, nbr[2].x};
    const float ty[5] = {nbr[0].y, c1y, nbr[1].y, c3y, nbr[2].y};
    const float tz[5] = {nbr[0].z, c1z, nbr[1].z, c3z, nbr[2].z};
    unsigned int wOwn[5];
#pragma unroll
    for (int c = 0; c < 5; ++c) {
        const float d0 = tx[c] - ctrO.x, d1 = ty[c] - ctrO.y, d2 = tz[c] - ctrO.z;
        float wv = SKN[DR * 5 + c] * __expf(-50.f * (d0 * d0 + d1 * d1 + d2 * d2));
        if (DR == 2 && c == 2) wv += 1.0f;   // identity (delta) spatial conv
        H2U cv; cv.h = __float2half2_rn(wv);
        wOwn[c] = cv.u;
    }
    unsigned int w0[5], w1[5];
#pragma unroll
    for (int c = 0; c < 5; ++c) {
        const unsigned int wo = (unsigned int)__shfl_xor((int)wOwn[c], 1);
        w0[c] = half ? wo : wOwn[c];         // cell0's weight
        w1[c] = half ? wOwn[c] : wo;         // cell1's weight
    }
#pragma unroll
    for (int g = 0; g < 3; ++g) {
        const __half2* bp = &bufQ[qoff + g][ly][ex0 - 2][0];
        const uint4 r0 = *reinterpret_cast<const uint4*>(bp);
        const uint4 r1 = *reinterpret_cast<const uint4*>(bp + 4);
        const uint4 r2 = *reinterpret_cast<const uint4*>(bp + 8);
        const unsigned int q01[6] = {r0.x, r0.z, r1.x, r1.z, r2.x, r2.z};
        const unsigned int q23[6] = {r0.y, r0.w, r1.y, r1.w, r2.y, r2.w};
#pragma unroll
        for (int c = 0; c < 5; ++c) {
            H2U wa; wa.u = w0[c];
            H2U p0; p0.u = q01[c]; H2U p1; p1.u = q23[c];
            a0[g][0] = __hfma2(wa.h, p0.h, a0[g][0]);
            a0[g][1] = __hfma2(wa.h, p1.h, a0[g][1]);
            H2U wb; wb.u = w1[c];
            H2U s0; s0.u = q01[c + 1]; H2U s1; s1.u = q23[c + 1];
            a1[g][0] = __hfma2(wb.h, s0.h, a1[g][0]);
            a1[g][1] = __hfma2(wb.h, s1.h, a1[g][1]);
        }
    }
}

// ---------------------------------------------------------------------------
// One mean-field iteration over the shrinking region; pair-per-2-threads with
// channel split. nq stash -> barrier -> in-place writeback (uint4 per quad).
// ---------------------------------------------------------------------------
template <int MARGIN, bool FINAL>
__device__ __forceinline__ void mf_iter(
        int tid, int b, int y0, int x0, int fast,
        const float* __restrict__ lgb, const float* __restrict__ scm,
        __half2 (*bufQ)[EH][EW][2], const float4* __restrict__ simg,
        float* __restrict__ outp) {
    constexpr int HT_ = EH - 2 * MARGIN, WT_ = EW - 2 * MARGIN;
    constexpr int WP = WT_ / 2, NPAIR = HT_ * WP, NACT = 2 * NPAIR;
    constexpr int NS = (NACT + NT - 1) / NT;
    const int half = tid & 1;
    const int qoff = half * 3;
    const int cbase = half ? 12 : 0;
    const int nch = half ? 9 : 12;

    unsigned int nq0[NS][6], nq1[NS][6];
    bool vld[NS];
    int eyA[NS], exA[NS];
#pragma unroll
    for (int s = 0; s < NS; ++s) {
        vld[s] = false;
        const int idx = tid + s * NT;
        if (idx < NACT) {
            const int pp = idx >> 1;
            const int pr = pp / WP, pc = pp % WP;
            const int ey = MARGIN + pr, ex0 = MARGIN + 2 * pc;
            eyA[s] = ey; exA[s] = ex0;
            const int gy = y0 + ey - HALO, gx0 = x0 + ex0 - HALO;
            // gx0 is always even and W even => cell validity is pair-uniform
            if ((unsigned)gy < H && (unsigned)gx0 < W) {
                vld[s] = true;
                const float4 ctrO = simg[ey * EW + ex0 + half];
                const __half2 zero2 = __float2half2_rn(0.f);
                __half2 aA0[3][2], aB0[3][2], aA1[3][2], aB1[3][2];
#pragma unroll
                for (int g = 0; g < 3; ++g) {
                    aA0[g][0] = zero2; aA0[g][1] = zero2;
                    aB0[g][0] = zero2; aB0[g][1] = zero2;
                    aA1[g][0] = zero2; aA1[g][1] = zero2;
                    aB1[g][0] = zero2; aB1[g][1] = zero2;
                }
                row_taps<0>(ey, ex0, half, qoff, simg, bufQ, ctrO, aA0, aA1);
                row_taps<1>(ey, ex0, half, qoff, simg, bufQ, ctrO, aA0, aA1);
                row_taps<2>(ey, ex0, half, qoff, simg, bufQ, ctrO, aA0, aA1);
                row_taps<3>(ey, ex0, half, qoff, simg, bufQ, ctrO, aB0, aB1);
                row_taps<4>(ey, ex0, half, qoff, simg, bufQ, ctrO, aB0, aB1);

                float m0[12], m1[12];
#pragma unroll
                for (int g = 0; g < 3; ++g) {
                    float2 lA = __half22float2(aA0[g][0]), lB = __half22float2(aB0[g][0]);
                    float2 hA = __half22float2(aA0[g][1]), hB = __half22float2(aB0[g][1]);
                    m0[4 * g + 0] = lA.x + lB.x; m0[4 * g + 1] = lA.y + lB.y;
                    m0[4 * g + 2] = hA.x + hB.x; m0[4 * g + 3] = hA.y + hB.y;
                    lA = __half22float2(aA1[g][0]); lB = __half22float2(aB1[g][0]);
                    hA = __half22float2(aA1[g][1]); hB = __half22float2(aB1[g][1]);
                    m1[4 * g + 0] = lA.x + lB.x; m1[4 * g + 1] = lA.y + lB.y;
                    m1[4 * g + 2] = hA.x + hB.x; m1[4 * g + 3] = hA.y + hB.y;
                }

                const float* lg2 = lgb + gy * W + gx0;
                float z0[12], z1[12];
                if (fast) {                   // compat == -I: z = logits + m
#pragma unroll
                    for (int cc = 0; cc < 12; ++cc) {
                        if (cc < nch) {
                            const float2 l2 = *reinterpret_cast<const float2*>(
                                &lg2[(size_t)(cbase + cc) * HW]);
                            z0[cc] = l2.x + m0[cc];
                            z1[cc] = l2.y + m1[cc];
                        } else { z0[cc] = -1e30f; z1[cc] = -1e30f; }
                    }
                } else {                      // general matvec, partner m via shfl
                    float pw0[12], pw1[12];
#pragma unroll
                    for (int cc = 0; cc < 12; ++cc) { pw0[cc] = 0.f; pw1[cc] = 0.f; }
#pragma unroll
                    for (int j = 0; j < 12; ++j) {
                        const float mo0 = __shfl_xor(m0[j], 1);
                        const float mo1 = __shfl_xor(m1[j], 1);
                        const int chS = cbase + j;          // own channel id
                        const int chO = (cbase ^ 12) + j;   // partner channel id
#pragma unroll
                        for (int cc = 0; cc < 12; ++cc) {
                            if (cc < nch) {
                                const int row = (cbase + cc) * C;
                                if (chS < C) {
                                    pw0[cc] += scm[row + chS] * m0[j];
                                    pw1[cc] += scm[row + chS] * m1[j];
                                }
                                if (chO < C) {
                                    pw0[cc] += scm[row + chO] * mo0;
                                    pw1[cc] += scm[row + chO] * mo1;
                                }
                            }
                        }
                    }
#pragma unroll
                    for (int cc = 0; cc < 12; ++cc) {
                        if (cc < nch) {
                            const float2 l2 = *reinterpret_cast<const float2*>(
                                &lg2[(size_t)(cbase + cc) * HW]);
                            z0[cc] = l2.x - pw0[cc];
                            z1[cc] = l2.y - pw1[cc];
                        } else { z0[cc] = -1e30f; z1[cc] = -1e30f; }
                    }
                }

                // softmax across the channel halves (lane 2i <-> 2i+1)
                float mx0 = -1e30f, mx1 = -1e30f;
#pragma unroll
                for (int cc = 0; cc < 12; ++cc) {
                    mx0 = fmaxf(mx0, z0[cc]); mx1 = fmaxf(mx1, z1[cc]);
                }
                mx0 = fmaxf(mx0, __shfl_xor(mx0, 1));
                mx1 = fmaxf(mx1, __shfl_xor(mx1, 1));
                float s0 = 0.f, s1 = 0.f;
#pragma unroll
                for (int cc = 0; cc < 12; ++cc) {
                    if (cc < nch) {
                        z0[cc] = __expf(z0[cc] - mx0); s0 += z0[cc];
                        z1[cc] = __expf(z1[cc] - mx1); s1 += z1[cc];
                    } else { z0[cc] = 0.f; z1[cc] = 0.f; }
                }
                s0 += __shfl_xor(s0, 1);
                s1 += __shfl_xor(s1, 1);
                const float i0 = 1.f / s0, i1 = 1.f / s1;

                if (FINAL) {
                    float* qo = outp + (size_t)b * C * HW + gy * W + gx0;
#pragma unroll
                    for (int cc = 0; cc < 12; ++cc)
                        if (cc < nch)
                            *reinterpret_cast<float2*>(&qo[(size_t)(cbase + cc) * HW]) =
                                make_float2(z0[cc] * i0, z1[cc] * i1);
                } else {
#pragma unroll
                    for (int g = 0; g < 3; ++g) {
                        H2U p0, p1;
                        p0.h = __floats2half2_rn(z0[4 * g + 0] * i0, z0[4 * g + 1] * i0);
                        p1.h = __floats2half2_rn(z0[4 * g + 2] * i0, z0[4 * g + 3] * i0);
                        nq0[s][2 * g] = p0.u; nq0[s][2 * g + 1] = p1.u;
                        p0.h = __floats2half2_rn(z1[4 * g + 0] * i1, z1[4 * g + 1] * i1);
                        p1.h = __floats2half2_rn(z1[4 * g + 2] * i1, z1[4 * g + 3] * i1);
                        nq1[s][2 * g] = p0.u; nq1[s][2 * g + 1] = p1.u;
                    }
                }
            }
        }
    }
    if (!FINAL) {
        __syncthreads();                 // all reads of old q done
#pragma unroll
        for (int s = 0; s < NS; ++s) {
            if (vld[s]) {
#pragma unroll
                for (int g = 0; g < 3; ++g)
                    *reinterpret_cast<uint4*>(&bufQ[qoff + g][eyA[s]][exA[s]][0]) =
                        make_uint4(nq0[s][2 * g], nq0[s][2 * g + 1],
                                   nq1[s][2 * g], nq1[s][2 * g + 1]);
            }
        }
        __syncthreads();                 // new q visible
    }
}

// ---------------------------------------------------------------------------
// Mega-fused CRF: q0 = softmax(logits) staged on a 36x52 extended tile, then
// all 5 mean-field iterations in-LDS with shrinking regions. One dispatch,
// 256 blocks (1/CU) x 1024 threads. LDS = 121.6 KB. waves_per_eu pinned to 4
// so the allocator uses the full 128-VGPR budget (R12 spilled chasing 8).
// ---------------------------------------------------------------------------
__global__ __launch_bounds__(NT)
__attribute__((amdgpu_waves_per_eu(4, 4)))
void crf_mega(
        const float* __restrict__ logits, const float* __restrict__ img,
        const float* __restrict__ compat, float* __restrict__ out) {
    __shared__ __align__(16) __half2 bufQ[CQ][EH][EW][2];  // 89856 B
    __shared__ __align__(16) float4 simg[NEC];             // 29952 B
    __shared__ float scm[C * C];                           // 1764 B

    const int b = blockIdx.z;
    const int x0 = blockIdx.x * TW, y0 = blockIdx.y * TH;
    const int tid = threadIdx.x;

    // ---- compat stage (+ -I check) ----
    int ok = 1;
    for (int i = tid; i < C * C; i += NT) {
        const float v = compat[i];
        scm[i] = v;
        ok &= (v == ((i / C == i % C) ? -1.0f : 0.0f));
    }

    const float* im  = img + (size_t)b * 3 * HW;
    const float* lgb = logits + (size_t)b * C * HW;

    // ---- stage img (f32) and q0 = softmax(logits) (fp16 quads) ----
    for (int cell = tid; cell < NEC; cell += NT) {
        const int ey = cell / EW, ex = cell % EW;
        const int gy = y0 + ey - HALO, gx = x0 + ex - HALO;
        float4 iv = make_float4(0.f, 0.f, 0.f, 0.f);
        float vals[24];
        if ((unsigned)gy < H && (unsigned)gx < W) {
            const int np = gy * W + gx;
            iv.x = im[np]; iv.y = im[HW + np]; iv.z = im[2 * HW + np];
            const float* lg = lgb + np;
            float zz[C], mx = -1e30f;
#pragma unroll
            for (int c = 0; c < C; ++c) {
                zz[c] = lg[(size_t)c * HW]; mx = fmaxf(mx, zz[c]);
            }
            float ssum = 0.f;
#pragma unroll
            for (int c = 0; c < C; ++c) { zz[c] = __expf(zz[c] - mx); ssum += zz[c]; }
            const float inv = 1.f / ssum;
#pragma unroll
            for (int c = 0; c < 24; ++c) vals[c] = (c < C) ? zz[c] * inv : 0.f;
        } else {
#pragma unroll
            for (int c = 0; c < 24; ++c) vals[c] = 0.f;
        }
        simg[cell] = iv;
#pragma unroll
        for (int g = 0; g < CQ; ++g) {
            bufQ[g][ey][ex][0] = __floats2half2_rn(vals[4 * g + 0], vals[4 * g + 1]);
            bufQ[g][ey][ex][1] = __floats2half2_rn(vals[4 * g + 2], vals[4 * g + 3]);
        }
    }
    const int fast = __syncthreads_and(ok);

    // ---- 5 fused iterations, shrinking regions (margins 2,4,6,8,10) ----
    mf_iter< 2, false>(tid, b, y0, x0, fast, lgb, scm, bufQ, simg, out);
    mf_iter< 4, false>(tid, b, y0, x0, fast, lgb, scm, bufQ, simg, out);
    mf_iter< 6, false>(tid, b, y0, x0, fast, lgb, scm, bufQ, simg, out);
    mf_iter< 8, false>(tid, b, y0, x0, fast, lgb, scm, bufQ, simg, out);
    mf_iter<10, true >(tid, b, y0, x0, fast, lgb, scm, bufQ, simg, out);
}

// ---------------------------------------------------------------------------
extern "C" void kernel_launch(void* const* d_in, const int* in_sizes, int n_in,
                              void* d_out, int out_size, void* d_ws, size_t ws_size,
                              hipStream_t stream) {
    const float* logits = (const float*)d_in[0];
    const float* img    = (const float*)d_in[1];
    // d_in[2] = gt_edges (dead code in reference)
    const float* compat = (const float*)d_in[3];
    float* out = (float*)d_out;

    dim3 g(W / TW, H / TH, Bn);      // 8 x 16 x 2 = 256 blocks = 1 per CU
    crf_mega<<<g, NT, 0, stream>>>(logits, img, compat, out);
}

// Round 14
// 61.781 us; speedup vs baseline: 10.1224x; 1.4095x over previous
//
#include <hip/hip_runtime.h>
#include <hip/hip_fp16.h>

constexpr int Bn = 2, C = 21, H = 256, W = 256, HW = H * W;
constexpr int CQ = 6;                     // channel quads (C padded to 24)
constexpr int TW = 32, THt = 8, NT = 512; // output tile / block size

// Normalized spatial gaussian (sigma=5): exp(-(dy^2+dx^2)/50)/S, S=23.1036923.
__device__ constexpr float SKN[25] = {
    0.03688346f, 0.03916421f, 0.03995538f, 0.03916421f, 0.03688346f,
    0.03916421f, 0.04158598f, 0.04242608f, 0.04158598f, 0.03916421f,
    0.03995538f, 0.04242608f, 0.04328314f, 0.04242608f, 0.03995538f,
    0.03916421f, 0.04158598f, 0.04242608f, 0.04158598f, 0.03916421f,
    0.03688346f, 0.03916421f, 0.03995538f, 0.03916421f, 0.03688346f};

union H2U { __half2 h; unsigned int u; };

// ---------------------------------------------------------------------------
// One mean-field iteration over the shrinking region (margin cells from the
// extended-tile edge). R11's proven cell body, geometry-templated.
// FINAL: writes f32 channel planes to outp (ws or d_out), no writeback.
// ---------------------------------------------------------------------------
template <int EHp, int EWp, int MARGIN, bool FINAL>
__device__ __forceinline__ void mf_iter(
        int tid, int b, int y0, int x0, int fast,
        const float* __restrict__ lgb, const float* __restrict__ scm,
        __half2 (*bufQ)[EHp][EWp][2], const float4* __restrict__ simg,
        float* __restrict__ outp) {
    constexpr int HALOP = (EHp - THt) / 2;
    constexpr int HT_ = EHp - 2 * MARGIN, WT_ = EWp - 2 * MARGIN;
    constexpr int NCEL = HT_ * WT_;
    constexpr int NS = (NCEL + NT - 1) / NT;
    unsigned int nq[NS][12];
    bool valid[NS];
#pragma unroll
    for (int s = 0; s < NS; ++s) {
        valid[s] = false;
        const int cell = tid + s * NT;
        if (cell < NCEL) {
            const int ry = cell / WT_, rx = cell % WT_;
            const int ey = MARGIN + ry, ex = MARGIN + rx;
            const int gy = y0 + ey - HALOP, gx = x0 + ex - HALOP;
            if ((unsigned)gy < H && (unsigned)gx < W) {
                valid[s] = true;
                const float* lgp = lgb + gy * W + gx;
                float lg[C];
#pragma unroll
                for (int c = 0; c < C; ++c) lg[c] = lgp[(size_t)c * HW];
                // ---- bilateral weights from LDS img tile ----
                const float4 ctr = simg[ey * EWp + ex];
                unsigned int wk[25];
#pragma unroll
                for (int k = 0; k < 25; ++k) {
                    const int dy = k / 5 - 2, dx = k % 5 - 2;
                    const float4 nb = simg[(ey + dy) * EWp + (ex + dx)];
                    const float d0 = nb.x - ctr.x, d1 = nb.y - ctr.y,
                                d2 = nb.z - ctr.z;
                    float wv = SKN[k] *
                        __expf(-50.f * (d0 * d0 + d1 * d1 + d2 * d2));
                    if (k == 12) wv += 1.0f;   // identity (delta) spatial conv
                    H2U cv; cv.h = __float2half2_rn(wv);
                    wk[k] = cv.u;
                }
                // ---- 25 taps x 6 quads, fp16 A/B partial accumulators ----
                const __half2 zero2 = __float2half2_rn(0.f);
                __half2 aA[CQ][2], aB[CQ][2];
#pragma unroll
                for (int g = 0; g < CQ; ++g) {
                    aA[g][0] = zero2; aA[g][1] = zero2;
                    aB[g][0] = zero2; aB[g][1] = zero2;
                }
#pragma unroll
                for (int k = 0; k < 25; ++k) {
                    const int ly = ey + k / 5 - 2, lx = ex + k % 5 - 2;
                    H2U wv; wv.u = wk[k];
#pragma unroll
                    for (int g = 0; g < CQ; ++g) {
                        const uint2 raw =
                            *reinterpret_cast<const uint2*>(&bufQ[g][ly][lx][0]);
                        H2U q01, q23; q01.u = raw.x; q23.u = raw.y;
                        if (k < 13) {
                            aA[g][0] = __hfma2(wv.h, q01.h, aA[g][0]);
                            aA[g][1] = __hfma2(wv.h, q23.h, aA[g][1]);
                        } else {
                            aB[g][0] = __hfma2(wv.h, q01.h, aB[g][0]);
                            aB[g][1] = __hfma2(wv.h, q23.h, aB[g][1]);
                        }
                    }
                }
                float m[24];
#pragma unroll
                for (int g = 0; g < CQ; ++g) {
                    const float2 lA = __half22float2(aA[g][0]);
                    const float2 lB = __half22float2(aB[g][0]);
                    const float2 hA = __half22float2(aA[g][1]);
                    const float2 hB = __half22float2(aB[g][1]);
                    m[4 * g + 0] = lA.x + lB.x;
                    m[4 * g + 1] = lA.y + lB.y;
                    m[4 * g + 2] = hA.x + hB.x;
                    m[4 * g + 3] = hA.y + hB.y;
                }
                // ---- compatibility + softmax (thread-local) ----
                float z[C], mx = -1e30f;
                if (fast) {                  // compat == -I: z = logits + m
#pragma unroll
                    for (int c = 0; c < C; ++c) {
                        z[c] = lg[c] + m[c]; mx = fmaxf(mx, z[c]);
                    }
                } else {
#pragma unroll
                    for (int c = 0; c < C; ++c) {
                        float pw = 0.f;
#pragma unroll
                        for (int j = 0; j < C; ++j) pw += scm[c * C + j] * m[j];
                        z[c] = lg[c] - pw; mx = fmaxf(mx, z[c]);
                    }
                }
                float ssum = 0.f;
#pragma unroll
                for (int c = 0; c < C; ++c) {
                    z[c] = __expf(z[c] - mx); ssum += z[c];
                }
                const float inv = 1.f / ssum;
                if (FINAL) {
                    float* qo = outp + (size_t)b * C * HW + gy * W + gx;
#pragma unroll
                    for (int c = 0; c < C; ++c) qo[(size_t)c * HW] = z[c] * inv;
                } else {
                    float vals[24];
#pragma unroll
                    for (int c = 0; c < 24; ++c)
                        vals[c] = (c < C) ? z[c] * inv : 0.f;
#pragma unroll
                    for (int g = 0; g < CQ; ++g) {
                        H2U p0; p0.h = __floats2half2_rn(vals[4 * g + 0], vals[4 * g + 1]);
                        H2U p1; p1.h = __floats2half2_rn(vals[4 * g + 2], vals[4 * g + 3]);
                        nq[s][2 * g + 0] = p0.u;
                        nq[s][2 * g + 1] = p1.u;
                    }
                }
            }
        }
    }
    if (!FINAL) {
        __syncthreads();                     // all reads of old q done
#pragma unroll
        for (int s = 0; s < NS; ++s) {
            if (valid[s]) {
                const int cell = tid + s * NT;
                const int ry = cell / WT_, rx = cell % WT_;
                const int ey = MARGIN + ry, ex = MARGIN + rx;
#pragma unroll
                for (int g = 0; g < CQ; ++g)
                    *reinterpret_cast<uint2*>(&bufQ[g][ey][ex][0]) =
                        make_uint2(nq[s][2 * g], nq[s][2 * g + 1]);
            }
        }
        __syncthreads();                     // new q visible
    }
}

// ---------------------------------------------------------------------------
// Phase kernel: stages q (INIT: q0 = softmax(logits); else f32 planes from
// qin) + img on the extended tile, then NIT in-LDS iterations (margins
// 2,4,..,2*NIT = HALOP). Last iteration writes f32 planes to qout.
// Tile 32x8, NT=512, grid 512 blocks -> 2 blocks/CU.
// ---------------------------------------------------------------------------
template <int HALOP, bool INIT, int NIT>
__global__ __launch_bounds__(NT, 4) void crf_phase(
        const float* __restrict__ qin, const float* __restrict__ logits,
        const float* __restrict__ img, const float* __restrict__ compat,
        float* __restrict__ qout) {
    constexpr int EHp = THt + 2 * HALOP, EWp = TW + 2 * HALOP;
    constexpr int NECp = EHp * EWp;
    __shared__ __align__(16) __half2 bufQ[CQ][EHp][EWp][2];
    __shared__ __align__(16) float4 simg[NECp];
    __shared__ float scm[C * C];

    const int b = blockIdx.z;
    const int x0 = blockIdx.x * TW, y0 = blockIdx.y * THt;
    const int tid = threadIdx.x;

    // ---- compat stage (+ -I check) ----
    int ok = 1;
    for (int i = tid; i < C * C; i += NT) {
        const float v = compat[i];
        scm[i] = v;
        ok &= (v == ((i / C == i % C) ? -1.0f : 0.0f));
    }

    const float* im  = img + (size_t)b * 3 * HW;
    const float* lgb = logits + (size_t)b * C * HW;

    // ---- stage img (f32 float4) and q (fp16 quads) ----
    for (int cell = tid; cell < NECp; cell += NT) {
        const int ey = cell / EWp, ex = cell % EWp;
        const int gy = y0 + ey - HALOP, gx = x0 + ex - HALOP;
        float4 iv = make_float4(0.f, 0.f, 0.f, 0.f);
        float vals[24];
        if ((unsigned)gy < H && (unsigned)gx < W) {
            const int np = gy * W + gx;
            iv.x = im[np]; iv.y = im[HW + np]; iv.z = im[2 * HW + np];
            if (INIT) {
                const float* lg = lgb + np;
                float zz[C], mx = -1e30f;
#pragma unroll
                for (int c = 0; c < C; ++c) {
                    zz[c] = lg[(size_t)c * HW]; mx = fmaxf(mx, zz[c]);
                }
                float ssum = 0.f;
#pragma unroll
                for (int c = 0; c < C; ++c) { zz[c] = __expf(zz[c] - mx); ssum += zz[c]; }
                const float inv = 1.f / ssum;
#pragma unroll
                for (int c = 0; c < 24; ++c) vals[c] = (c < C) ? zz[c] * inv : 0.f;
            } else {
                const float* qp = qin + (size_t)b * C * HW + np;
#pragma unroll
                for (int c = 0; c < 24; ++c)
                    vals[c] = (c < C) ? qp[(size_t)c * HW] : 0.f;
            }
        } else {
#pragma unroll
            for (int c = 0; c < 24; ++c) vals[c] = 0.f;
        }
        simg[cell] = iv;
#pragma unroll
        for (int g = 0; g < CQ; ++g) {
            bufQ[g][ey][ex][0] = __floats2half2_rn(vals[4 * g + 0], vals[4 * g + 1]);
            bufQ[g][ey][ex][1] = __floats2half2_rn(vals[4 * g + 2], vals[4 * g + 3]);
        }
    }
    const int fast = __syncthreads_and(ok);

    // ---- NIT fused iterations, shrinking regions ----
    mf_iter<EHp, EWp, 2, (NIT == 1)>(tid, b, y0, x0, fast, lgb, scm, bufQ, simg, qout);
    if constexpr (NIT >= 2)
        mf_iter<EHp, EWp, 4, (NIT == 2)>(tid, b, y0, x0, fast, lgb, scm, bufQ, simg, qout);
    if constexpr (NIT >= 3)
        mf_iter<EHp, EWp, 6, (NIT == 3)>(tid, b, y0, x0, fast, lgb, scm, bufQ, simg, qout);
}

// ---------------------------------------------------------------------------
extern "C" void kernel_launch(void* const* d_in, const int* in_sizes, int n_in,
                              void* d_out, int out_size, void* d_ws, size_t ws_size,
                              hipStream_t stream) {
    const float* logits = (const float*)d_in[0];
    const float* img    = (const float*)d_in[1];
    // d_in[2] = gt_edges (dead code in reference)
    const float* compat = (const float*)d_in[3];
    float* out = (float*)d_out;
    float* q3  = (float*)d_ws;                  // Bn*C*HW f32 (phase boundary)

    dim3 g(W / TW, H / THt, Bn);                // 8 x 32 x 2 = 512 blocks
    // Phase A: q0 inline, iterations 1-3 (halo 6) -> q3
    crf_phase<6, true, 3><<<g, NT, 0, stream>>>(nullptr, logits, img, compat, q3);
    // Phase B: stage q3, iterations 4-5 (halo 4) -> out
    crf_phase<4, false, 2><<<g, NT, 0, stream>>>(q3, logits, img, compat, out);
}

// Round 17
// 53.108 us; speedup vs baseline: 11.7755x; 1.1633x over previous
//
#include <hip/hip_runtime.h>
#include <hip/hip_fp16.h>

constexpr int Bn = 2, C = 21, H = 256, W = 256, HW = H * W;
constexpr int GP = 3;                       // quad-pairs (8 channels per 16B)
constexpr int TW = 32, TH = 16, NT = 1024;  // output tile / block size
constexpr int HALO = 10;                    // 5 iterations x 2-halo
constexpr int EH = TH + 2 * HALO;           // 36
constexpr int EW = TW + 2 * HALO;           // 52
constexpr int NEC = EH * EW;                // 1872

// Normalized spatial gaussian (sigma=5): exp(-(dy^2+dx^2)/50)/S, S=23.1036923.
__device__ constexpr float SKN[25] = {
    0.03688346f, 0.03916421f, 0.03995538f, 0.03916421f, 0.03688346f,
    0.03916421f, 0.04158598f, 0.04242608f, 0.04158598f, 0.03916421f,
    0.03995538f, 0.04242608f, 0.04328314f, 0.04242608f, 0.03995538f,
    0.03916421f, 0.04158598f, 0.04242608f, 0.04158598f, 0.03916421f,
    0.03688346f, 0.03916421f, 0.03995538f, 0.03916421f, 0.03688346f};

union H2U { __half2 h; unsigned int u; };

__device__ __forceinline__ unsigned int packh2(float a, float b) {
    H2U u; u.h = __floats2half2_rn(a, b); return u.u;
}

// ---------------------------------------------------------------------------
// One mean-field iteration over the shrinking region (margin cells from the
// extended-tile edge). R11's cell body with quad-paired b128 LDS layout.
// ---------------------------------------------------------------------------
template <int MARGIN, bool FINAL>
__device__ __forceinline__ void mf_iter(
        int tid, int b, int y0, int x0, int fast,
        const float* __restrict__ lgb, const float* __restrict__ scm,
        uint4 (*bufQ)[EH][EW], const uint2* __restrict__ simgh,
        float* __restrict__ outp) {
    constexpr int HT_ = EH - 2 * MARGIN, WT_ = EW - 2 * MARGIN;
    constexpr int NCEL = HT_ * WT_;
    constexpr int NS = (NCEL + NT - 1) / NT;
    uint4 nq[NS][GP];
    bool valid[NS];
#pragma unroll
    for (int s = 0; s < NS; ++s) {
        valid[s] = false;
        const int cell = tid + s * NT;
        if (cell < NCEL) {
            const int ry = cell / WT_, rx = cell % WT_;
            const int ey = MARGIN + ry, ex = MARGIN + rx;
            const int gy = y0 + ey - HALO, gx = x0 + ex - HALO;
            if ((unsigned)gy < H && (unsigned)gx < W) {
                valid[s] = true;
                // ---- logits (issued early, hidden under the exp chain) ----
                const float* lgp = lgb + gy * W + gx;
                float lg[C];
#pragma unroll
                for (int c = 0; c < C; ++c) lg[c] = lgp[(size_t)c * HW];
                // ---- bilateral weights from fp16 LDS img tile ----
                float cr, cg, cb;
                {
                    const uint2 cc2 = simgh[ey * EW + ex];
                    H2U a; a.u = cc2.x; const float2 rg = __half22float2(a.h);
                    H2U d; d.u = cc2.y; const float2 bz = __half22float2(d.h);
                    cr = rg.x; cg = rg.y; cb = bz.x;
                }
                unsigned int wk[25];
#pragma unroll
                for (int k = 0; k < 25; ++k) {
                    const int dy = k / 5 - 2, dx = k % 5 - 2;
                    const uint2 n2 = simgh[(ey + dy) * EW + (ex + dx)];
                    H2U a; a.u = n2.x; const float2 rg = __half22float2(a.h);
                    H2U d; d.u = n2.y; const float2 bz = __half22float2(d.h);
                    const float d0 = rg.x - cr, d1 = rg.y - cg, d2 = bz.x - cb;
                    float wv = SKN[k] *
                        __expf(-50.f * (d0 * d0 + d1 * d1 + d2 * d2));
                    if (k == 12) wv += 1.0f;   // identity (delta) spatial conv
                    wk[k] = packh2(wv, wv);
                }
                // ---- 25 taps x 3 b128 quad-pair reads, fp16 A/B partials ---
                const __half2 zero2 = __float2half2_rn(0.f);
                __half2 aA[GP][4], aB[GP][4];
#pragma unroll
                for (int g = 0; g < GP; ++g)
#pragma unroll
                    for (int j = 0; j < 4; ++j) { aA[g][j] = zero2; aB[g][j] = zero2; }
#pragma unroll
                for (int k = 0; k < 25; ++k) {
                    const int ly = ey + k / 5 - 2, lx = ex + k % 5 - 2;
                    H2U wv; wv.u = wk[k];
#pragma unroll
                    for (int g = 0; g < GP; ++g) {
                        const uint4 raw = bufQ[g][ly][lx];
                        H2U q0, q1, q2, q3;
                        q0.u = raw.x; q1.u = raw.y; q2.u = raw.z; q3.u = raw.w;
                        if (k < 13) {
                            aA[g][0] = __hfma2(wv.h, q0.h, aA[g][0]);
                            aA[g][1] = __hfma2(wv.h, q1.h, aA[g][1]);
                            aA[g][2] = __hfma2(wv.h, q2.h, aA[g][2]);
                            aA[g][3] = __hfma2(wv.h, q3.h, aA[g][3]);
                        } else {
                            aB[g][0] = __hfma2(wv.h, q0.h, aB[g][0]);
                            aB[g][1] = __hfma2(wv.h, q1.h, aB[g][1]);
                            aB[g][2] = __hfma2(wv.h, q2.h, aB[g][2]);
                            aB[g][3] = __hfma2(wv.h, q3.h, aB[g][3]);
                        }
                    }
                }
                float m[24];
#pragma unroll
                for (int g = 0; g < GP; ++g)
#pragma unroll
                    for (int j = 0; j < 4; ++j) {
                        const float2 fA = __half22float2(aA[g][j]);
                        const float2 fB = __half22float2(aB[g][j]);
                        m[8 * g + 2 * j + 0] = fA.x + fB.x;
                        m[8 * g + 2 * j + 1] = fA.y + fB.y;
                    }
                // ---- compatibility + softmax (thread-local) ----
                float z[C], mx = -1e30f;
                if (fast) {                  // compat == -I: z = logits + m
#pragma unroll
                    for (int c = 0; c < C; ++c) {
                        z[c] = lg[c] + m[c]; mx = fmaxf(mx, z[c]);
                    }
                } else {                     // general matvec, local
#pragma unroll
                    for (int c = 0; c < C; ++c) {
                        float pw = 0.f;
#pragma unroll
                        for (int j = 0; j < C; ++j) pw += scm[c * C + j] * m[j];
                        z[c] = lg[c] - pw; mx = fmaxf(mx, z[c]);
                    }
                }
                float ssum = 0.f;
#pragma unroll
                for (int c = 0; c < C; ++c) {
                    z[c] = __expf(z[c] - mx); ssum += z[c];
                }
                const float inv = 1.f / ssum;
                if (FINAL) {
                    float* qo = outp + (size_t)b * C * HW + gy * W + gx;
#pragma unroll
                    for (int c = 0; c < C; ++c) qo[(size_t)c * HW] = z[c] * inv;
                } else {
                    float vals[24];
#pragma unroll
                    for (int c = 0; c < 24; ++c)
                        vals[c] = (c < C) ? z[c] * inv : 0.f;
#pragma unroll
                    for (int g = 0; g < GP; ++g)
                        nq[s][g] = make_uint4(
                            packh2(vals[8 * g + 0], vals[8 * g + 1]),
                            packh2(vals[8 * g + 2], vals[8 * g + 3]),
                            packh2(vals[8 * g + 4], vals[8 * g + 5]),
                            packh2(vals[8 * g + 6], vals[8 * g + 7]));
                }
            }
        }
    }
    if (!FINAL) {
        __syncthreads();                     // all reads of old q done
#pragma unroll
        for (int s = 0; s < NS; ++s) {
            if (valid[s]) {
                const int cell = tid + s * NT;
                const int ry = cell / WT_, rx = cell % WT_;
                const int ey = MARGIN + ry, ex = MARGIN + rx;
#pragma unroll
                for (int g = 0; g < GP; ++g) bufQ[g][ey][ex] = nq[s][g];
            }
        }
        __syncthreads();                     // new q visible
    }
}

// ---------------------------------------------------------------------------
// Mega-fused CRF: q0 = softmax(logits) staged on a 36x52 extended tile, then
// all 5 mean-field iterations in-LDS with shrinking regions. One dispatch,
// 256 blocks (1/CU) x 1024 threads. LDS = 106.6 KB (quad-paired q + fp16 img).
// ---------------------------------------------------------------------------
__global__ __launch_bounds__(NT, 4) void crf_mega(
        const float* __restrict__ logits, const float* __restrict__ img,
        const float* __restrict__ compat, float* __restrict__ out) {
    __shared__ __align__(16) uint4 bufQ[GP][EH][EW];   // 89856 B
    __shared__ __align__(16) uint2 simgh[NEC];         // 14976 B
    __shared__ float scm[C * C];                       // 1764 B

    const int b = blockIdx.z;
    const int x0 = blockIdx.x * TW, y0 = blockIdx.y * TH;
    const int tid = threadIdx.x;

    // ---- compat stage (+ -I check) ----
    int ok = 1;
    for (int i = tid; i < C * C; i += NT) {
        const float v = compat[i];
        scm[i] = v;
        ok &= (v == ((i / C == i % C) ? -1.0f : 0.0f));
    }

    const float* im  = img + (size_t)b * 3 * HW;
    const float* lgb = logits + (size_t)b * C * HW;

    // ---- stage img (packed fp16 rgb) and q0 = softmax(logits) (fp16) ----
    for (int cell = tid; cell < NEC; cell += NT) {
        const int ey = cell / EW, ex = cell % EW;
        const int gy = y0 + ey - HALO, gx = x0 + ex - HALO;
        float ir = 0.f, ig = 0.f, ib = 0.f;
        float vals[24];
        if ((unsigned)gy < H && (unsigned)gx < W) {
            const int np = gy * W + gx;
            ir = im[np]; ig = im[HW + np]; ib = im[2 * HW + np];
            const float* lg = lgb + np;
            float zz[C], mx = -1e30f;
#pragma unroll
            for (int c = 0; c < C; ++c) {
                zz[c] = lg[(size_t)c * HW]; mx = fmaxf(mx, zz[c]);
            }
            float ssum = 0.f;
#pragma unroll
            for (int c = 0; c < C; ++c) { zz[c] = __expf(zz[c] - mx); ssum += zz[c]; }
            const float inv = 1.f / ssum;
#pragma unroll
            for (int c = 0; c < 24; ++c) vals[c] = (c < C) ? zz[c] * inv : 0.f;
        } else {
#pragma unroll
            for (int c = 0; c < 24; ++c) vals[c] = 0.f;
        }
        simgh[cell] = make_uint2(packh2(ir, ig), packh2(ib, 0.f));
#pragma unroll
        for (int g = 0; g < GP; ++g)
            bufQ[g][ey][ex] = make_uint4(
                packh2(vals[8 * g + 0], vals[8 * g + 1]),
                packh2(vals[8 * g + 2], vals[8 * g + 3]),
                packh2(vals[8 * g + 4], vals[8 * g + 5]),
                packh2(vals[8 * g + 6], vals[8 * g + 7]));
    }
    const int fast = __syncthreads_and(ok);

    // ---- 5 fused iterations, shrinking regions (margins 2,4,6,8,10) ----
    mf_iter< 2, false>(tid, b, y0, x0, fast, lgb, scm, bufQ, simgh, out);
    mf_iter< 4, false>(tid, b, y0, x0, fast, lgb, scm, bufQ, simgh, out);
    mf_iter< 6, false>(tid, b, y0, x0, fast, lgb, scm, bufQ, simgh, out);
    mf_iter< 8, false>(tid, b, y0, x0, fast, lgb, scm, bufQ, simgh, out);
    mf_iter<10, true >(tid, b, y0, x0, fast, lgb, scm, bufQ, simgh, out);
}

// ---------------------------------------------------------------------------
extern "C" void kernel_launch(void* const* d_in, const int* in_sizes, int n_in,
                              void* d_out, int out_size, void* d_ws, size_t ws_size,
                              hipStream_t stream) {
    const float* logits = (const float*)d_in[0];
    const float* img    = (const float*)d_in[1];
    // d_in[2] = gt_edges (dead code in reference)
    const float* compat = (const float*)d_in[3];
    float* out = (float*)d_out;

    dim3 g(W / TW, H / TH, Bn);      // 8 x 16 x 2 = 256 blocks = 1 per CU
    crf_mega<<<g, NT, 0, stream>>>(logits, img, compat, out);
}